// Round 1
// baseline (235.823 us; speedup 1.0000x reference)
//
#include <hip/hip_runtime.h>
#include <hip/hip_bf16.h>
#include <math.h>

#define D_MODEL 1024
#define HD 128
#define SEQ 4096

typedef __bf16 bf16x8 __attribute__((ext_vector_type(8)));
typedef float f32x4 __attribute__((ext_vector_type(4)));
typedef unsigned int u32;
typedef u32 u32x4 __attribute__((ext_vector_type(4)));

__device__ __forceinline__ unsigned short f2bf(float f) {
    union { float f; u32 u; } c; c.f = f;
    u32 u = c.u;
    u = (u + 0x7fffu + ((u >> 16) & 1u)) >> 16;
    return (unsigned short)u;
}
__device__ __forceinline__ u32 pk2(float a, float b) {
    __hip_bfloat162 h = __float22bfloat162_rn(make_float2(a, b));
    union { __hip_bfloat162 h; u32 u; } c; c.h = h; return c.u;
}
// async global->LDS, 16B/lane; dest = wave-uniform base + lane*16  (attn only)
__device__ __forceinline__ void dma16(void* lds, const void* g) {
    __builtin_amdgcn_global_load_lds(
        (const __attribute__((address_space(1))) u32*)g,
        (__attribute__((address_space(3))) u32*)lds, 16, 0, 0);
}
// DMA completion is tracked only in the ISSUING wave's vmcnt (R7 race).
__device__ __forceinline__ void drain_dma()  { __builtin_amdgcn_s_waitcnt(0x0F70); } // vmcnt(0)

// ---------------------------------------------------------------------------
// LDS-transposed W -> Wt[n][k] bf16, n in [0,384). Q slice pre-scaled by
// 1/sqrt(128)*log2(e): scores exit QK^T MFMA in the log2 domain.
__global__ __launch_bounds__(256)
void wt_kernel(const float* __restrict__ Wq, const float* __restrict__ Wk,
               const float* __restrict__ Wv, unsigned short* __restrict__ Wt) {
    __shared__ float wsf[64][129];
    const int t = threadIdx.x;
    const int k0 = blockIdx.x * 64;
    const int mat = blockIdx.y;
    const float* W = (mat == 0) ? Wq : (mat == 1) ? Wk : Wv;
    const float sc = (mat == 0) ? (0.08838834764831845f * 1.4426950408889634f) : 1.0f;
    {
        const int r = t >> 2, c = (t & 3) * 32;
        const float* src = W + (size_t)(k0 + r) * HD + c;
        #pragma unroll
        for (int j = 0; j < 32; j += 4)
            *reinterpret_cast<f32x4*>(&wsf[r][c + j]) = *reinterpret_cast<const f32x4*>(src + j);
    }
    __syncthreads();
    const int n = t >> 1, ks = (t & 1) * 32;
    u32 ow[16];
    #pragma unroll
    for (int j = 0; j < 16; ++j)
        ow[j] = pk2(wsf[ks + 2 * j][n] * sc, wsf[ks + 2 * j + 1][n] * sc);
    unsigned short* dst = Wt + (size_t)(mat * HD + n) * D_MODEL + k0 + ks;
    #pragma unroll
    for (int j = 0; j < 4; ++j)
        *reinterpret_cast<u32x4*>(dst + j * 8) = (u32x4){ow[4*j], ow[4*j+1], ow[4*j+2], ow[4*j+3]};
}

// ---------------------------------------------------------------------------
// QKV projection v2: LDS-free, BARRIER-free, direct-to-register.
// Rationale (R10): v1's DMA->LDS->barrier loop stalled ~90% of each K-step on
// vmcnt (MfmaUtil 9.5%, ~3.3k cy/iter vs ~300 cy of issue work) -- per-wave
// in-flight capped at 8KB and the barrier coupled all 4 waves to the slowest
// DMA. But within a block nothing needs LDS: A-frags (8 contiguous k f32 of a
// private x row) and B-frags (16B of the [n][k]-transposed Wt) are both direct
// contiguous loads. Cross-wave Wt reuse -> L1 (24KB/CU working set); cross-
// block x reuse (Q/K/V siblings 8 ids apart -> same XCD) -> L2, as before.
// Depth-2 named-stage pipeline; SSA renaming lets the scheduler deepen it.
struct PStage { f32x4 a0, a1; bf16x8 b[8]; };

__device__ __forceinline__ void ld_stage(PStage& S, const float* xq,
                                         const unsigned short* wq) {
    S.a0 = *reinterpret_cast<const f32x4*>(xq);
    S.a1 = *reinterpret_cast<const f32x4*>(xq + 4);
    #pragma unroll
    for (int nt = 0; nt < 8; ++nt)
        S.b[nt] = *reinterpret_cast<const bf16x8*>(wq + nt * 16 * D_MODEL);
}
__device__ __forceinline__ void do_stage(const PStage& S, f32x4* acc) {
    union { u32 d[4]; bf16x8 v; } cva;
    cva.d[0] = pk2(S.a0[0], S.a0[1]); cva.d[1] = pk2(S.a0[2], S.a0[3]);
    cva.d[2] = pk2(S.a1[0], S.a1[1]); cva.d[3] = pk2(S.a1[2], S.a1[3]);
    bf16x8 af = cva.v;
    #pragma unroll
    for (int nt = 0; nt < 8; ++nt)
        acc[nt] = __builtin_amdgcn_mfma_f32_16x16x32_bf16(af, S.b[nt], acc[nt], 0, 0, 0);
}

__global__ __launch_bounds__(256, 3)
void proj_kernel(const float* __restrict__ x, const unsigned short* __restrict__ Wt,
                 unsigned short* __restrict__ Qb, unsigned short* __restrict__ Kb,
                 unsigned short* __restrict__ Vt) {
    const int t = threadIdx.x;
    const int w = t >> 6, l = t & 63, li = l & 15, g2 = l >> 4;
    const int id = blockIdx.x;                 // 0..767
    const int grp = id / 24, win = id % 24;
    const int nbase = (win >> 3) * 128;        // slice 0:Q 1:K 2:V
    const int rowbase = (grp * 8 + (win & 7)) * 64;

    // A: lane li -> row w*16+li, g2 -> k-offset g2*8 (8 consecutive f32)
    const float* xq = x + (size_t)(rowbase + w * 16 + li) * D_MODEL + g2 * 8;
    // B: lane li -> Wt row nbase+nt*16+li, same k-offset (8 bf16 = 16B, b128)
    const unsigned short* wq = Wt + (size_t)(nbase + li) * D_MODEL + g2 * 8;

    f32x4 acc[8];
    #pragma unroll
    for (int nt = 0; nt < 8; ++nt) acc[nt] = (f32x4){0.f, 0.f, 0.f, 0.f};

    PStage S0, S1;
    ld_stage(S0, xq, wq);
    ld_stage(S1, xq + 32, wq + 32);

    // steps 0..29 consumed in-loop (loads run 2 steps ahead), 30..31 in tail
    for (int it = 0; it < 30; it += 2) {
        do_stage(S0, acc);
        ld_stage(S0, xq + 64, wq + 64);
        do_stage(S1, acc);
        ld_stage(S1, xq + 96, wq + 96);
        xq += 64; wq += 64;
    }
    do_stage(S0, acc);
    do_stage(S1, acc);

    if (nbase < 256) {
        unsigned short* P = nbase ? Kb : Qb;
        #pragma unroll
        for (int nt = 0; nt < 8; ++nt)
            #pragma unroll
            for (int r = 0; r < 4; ++r) {
                int grow = rowbase + w * 16 + g2 * 4 + r;
                P[(size_t)grow * HD + nt * 16 + li] = f2bf(acc[nt][r]);
            }
    } else {
        int grow0 = rowbase + w * 16 + g2 * 4;
        int b_ = grow0 >> 12, s_ = grow0 & 4095;
        #pragma unroll
        for (int nt = 0; nt < 8; ++nt) {
            ushort4 s4;
            s4.x = f2bf(acc[nt][0]); s4.y = f2bf(acc[nt][1]);
            s4.z = f2bf(acc[nt][2]); s4.w = f2bf(acc[nt][3]);
            *reinterpret_cast<ushort4*>(&Vt[((size_t)b_ * HD + nt * 16 + li) * SEQ + s_]) = s4;
        }
    }
}

// ---------------------------------------------------------------------------
// Flash causal attention, OPERAND-SWAPPED: scores computed as K.Q^T so the
// C-layout gives each lane 4 CONTIGUOUS keys for one query column. Softmax
// row-sum becomes a per-lane scalar; P^T packs to one b64 LDS write per frag;
// PV runs as A=V(d,k), B=P^T(k,q); O exits q=lane/d-contiguous -> f32x4 stores.
// Double-buffered K/V DMA staging (one barrier/iter), fixed-shift softmax.
// LDS 72 KB: K/V buf0 [0,32K), buf1 [32K,64K), P^T [64K,72K).
__global__ __launch_bounds__(256, 2)
void attn_kernel(const unsigned short* __restrict__ Qb, const unsigned short* __restrict__ Kb,
                 const unsigned short* __restrict__ Vt, float* __restrict__ outO,
                 unsigned short* __restrict__ Obf, float* __restrict__ Lbuf) {
    __shared__ __align__(1024) char smem[73728];
    const int t = threadIdx.x;
    const int w = t >> 6, l = t & 63, li = l & 15, g2 = l >> 4;
    const int qh = w >> 1, kh = w & 1;
    const int b = blockIdx.x & 3;
    const int u = blockIdx.x >> 2;
    const int g = 63 - (u >> 2);               // q-group, heavy first (LPT)
    const int c = u & 3;                       // key-range chunk
    const int R = g + 1;
    const int ts = (c * R) >> 2, te = ((c + 1) * R) >> 2;
    const int q0 = g * 64;
    const size_t rowb = (size_t)b * SEQ;
    const int koff = kh * 32;

    const unsigned short* KbB = Kb + rowb * HD;
    const unsigned short* VtB = Vt + (size_t)b * HD * SEQ;
    const int vgran = ((l & 7) ^ (l >> 3)) * 8;

    auto stage = [&](int it, char* base) {
        const int j0 = it * 64;
        #pragma unroll
        for (int j = 0; j < 4; ++j) {
            int rK = w * 16 + 4 * j + (l >> 4);
            dma16(base + (w * 16 + 4 * j) * 256,
                  KbB + (size_t)(j0 + rK) * 128 + (((l & 15) ^ (rK & 7)) * 8));
            int rV = w * 32 + 8 * j + (l >> 3);
            dma16(base + 16384 + (w * 32 + 8 * j) * 128,
                  VtB + (size_t)rV * SEQ + j0 + vgran);
        }
    };

    // Q as B-operand: B[k=d][n=q], lane n=li -> q, 8 contiguous d (= row-major load)
    bf16x8 qf[2][4];
    #pragma unroll
    for (int qt = 0; qt < 2; ++qt)
        #pragma unroll
        for (int ks = 0; ks < 4; ++ks)
            qf[qt][ks] = *reinterpret_cast<const bf16x8*>(
                Qb + (rowb + q0 + qh * 32 + qt * 16 + li) * HD + ks * 32 + g2 * 8);

    f32x4 acco[2][8];        // [qt][dt]: q=li, d=dt*16+g2*4+r
    #pragma unroll
    for (int qt = 0; qt < 2; ++qt)
        #pragma unroll
        for (int dt = 0; dt < 8; ++dt) acco[qt][dt] = (f32x4){0.f, 0.f, 0.f, 0.f};
    float ls[2] = {0.f, 0.f};   // per-lane: column q=li (per qt tile)

    const int gV = ((4 * kh + g2) ^ (li & 7)) * 16;   // V read granule offset

    if (ts < te) stage(ts, smem);
    for (int it = ts; it < te; ++it) {
        char* cbuf = smem + ((it - ts) & 1) * 32768;
        char* nbuf = smem + (((it - ts) & 1) ^ 1) * 32768;
        drain_dma();
        __syncthreads();
        if (it + 1 < te) stage(it + 1, nbuf);   // overlaps compute below

        // S^T = K.Q^T : rows=key (koff+kt*16+g2*4+r), cols=q (li)
        f32x4 accs[2][2];
        #pragma unroll
        for (int qt = 0; qt < 2; ++qt)
            #pragma unroll
            for (int kt = 0; kt < 2; ++kt) accs[qt][kt] = (f32x4){0.f, 0.f, 0.f, 0.f};
        #pragma unroll
        for (int kt = 0; kt < 2; ++kt) {
            const char* kb = cbuf + (koff + kt * 16 + li) * 256;
            #pragma unroll
            for (int ks = 0; ks < 4; ++ks) {
                bf16x8 kf = *reinterpret_cast<const bf16x8*>(kb + (((4 * ks + g2) ^ (li & 7)) * 16));
                accs[0][kt] = __builtin_amdgcn_mfma_f32_16x16x32_bf16(kf, qf[0][ks], accs[0][kt], 0, 0, 0);
                accs[1][kt] = __builtin_amdgcn_mfma_f32_16x16x32_bf16(kf, qf[1][ks], accs[1][kt], 0, 0, 0);
            }
        }

        const bool masked = (it == g);
        #pragma unroll
        for (int qt = 0; qt < 2; ++qt) {
            const int prow = qh * 32 + qt * 16 + li;       // block-local q
            #pragma unroll
            for (int kt = 0; kt < 2; ++kt) {
                float p[4];
                #pragma unroll
                for (int r = 0; r < 4; ++r) {
                    float s = accs[qt][kt][r];
                    if (masked && (koff + kt * 16 + g2 * 4 + r > prow)) s = -INFINITY;
                    p[r] = __builtin_amdgcn_exp2f(s - 16.0f);
                    ls[qt] += p[r];
                }
                // P^T[q][key] : lane writes 4 contiguous keys = one b64 store
                union { u32 d[2]; uint2 v; } pw;
                pw.d[0] = pk2(p[0], p[1]); pw.d[1] = pk2(p[2], p[3]);
                int gr = (kh * 4 + kt * 2 + (g2 >> 1)) ^ (prow & 7);
                *reinterpret_cast<uint2*>(
                    smem + 65536 + prow * 128 + gr * 16 + (g2 & 1) * 8) = pw.v;
            }
        }

        // In-wave P^T write->read only (same rows/granules); lgkmcnt orders.
        bf16x8 pb[2];
        #pragma unroll
        for (int qt = 0; qt < 2; ++qt) {
            const int prow = qh * 32 + qt * 16 + li;
            pb[qt] = *reinterpret_cast<const bf16x8*>(
                smem + 65536 + prow * 128 + (((kh * 4 + g2) ^ (prow & 7)) * 16));
        }
        #pragma unroll
        for (int dt = 0; dt < 8; ++dt) {
            bf16x8 va = *reinterpret_cast<const bf16x8*>(cbuf + 16384 + (dt * 16 + li) * 128 + gV);
            acco[0][dt] = __builtin_amdgcn_mfma_f32_16x16x32_bf16(va, pb[0], acco[0][dt], 0, 0, 0);
            acco[1][dt] = __builtin_amdgcn_mfma_f32_16x16x32_bf16(va, pb[1], acco[1][dt], 0, 0, 0);
        }
    }

    // per-lane l: combine the 4 key-quads (lanes 16 apart hold same q)
    #pragma unroll
    for (int qt = 0; qt < 2; ++qt) {
        ls[qt] += __shfl_xor(ls[qt], 16);
        ls[qt] += __shfl_xor(ls[qt], 32);
    }

    // combine kh halves via LDS overlay (stage buffers dead now)
    float (*Osum)[132] = (float(*)[132])smem;        // 64 x 128 (+4 pad) f32 = [0,33792)
    float* Lsh = (float*)(smem + 33792);             // [2][64]
    __syncthreads();
    if (l < 16) {
        Lsh[kh * 64 + qh * 32 + l]      = ls[0];
        Lsh[kh * 64 + qh * 32 + 16 + l] = ls[1];
    }
    if (kh == 0) {
        #pragma unroll
        for (int qt = 0; qt < 2; ++qt)
            #pragma unroll
            for (int dt = 0; dt < 8; ++dt)
                *reinterpret_cast<f32x4*>(
                    &Osum[qh * 32 + qt * 16 + li][dt * 16 + g2 * 4]) = acco[qt][dt];
    }
    __syncthreads();
    if (kh == 1) {
        #pragma unroll
        for (int qt = 0; qt < 2; ++qt)
            #pragma unroll
            for (int dt = 0; dt < 8; ++dt) {
                f32x4* p = reinterpret_cast<f32x4*>(
                    &Osum[qh * 32 + qt * 16 + li][dt * 16 + g2 * 4]);
                f32x4 v = *p;
                #pragma unroll
                for (int j = 0; j < 4; ++j) v[j] += acco[qt][dt][j];
                *p = v;
            }
    }
    __syncthreads();

    if (t < 64)
        Lbuf[(size_t)c * 16384 + rowb + q0 + t] = Lsh[t] + Lsh[64 + t];
    #pragma unroll
    for (int k = 0; k < 8; ++k) {
        int idx = t + k * 256;
        int row = idx >> 5, col = (idx & 31) * 4;
        f32x4 o = *reinterpret_cast<const f32x4*>(&Osum[row][col]);
        size_t grow = rowb + q0 + row;
        if (c == 3) {
            *reinterpret_cast<f32x4*>(&outO[grow * HD + col]) = o;
        } else {
            union { u32 d[2]; uint2 v; } pkd;
            pkd.d[0] = pk2(o[0], o[1]); pkd.d[1] = pk2(o[2], o[3]);
            *reinterpret_cast<uint2*>(&Obf[(size_t)c * 2097152 + grow * HD + col]) = pkd.v;
        }
    }
}

// ---------------------------------------------------------------------------
// Merge: out = (Obf[0]+Obf[1]+Obf[2]+out) / (l0+l1+l2+l3)
__global__ __launch_bounds__(256)
void merge_kernel(float* __restrict__ outO, const unsigned short* __restrict__ Obf,
                  const float* __restrict__ Lbuf) {
    int tid = blockIdx.x * 256 + threadIdx.x;
    #pragma unroll
    for (int k = 0; k < 4; ++k) {
        int idx = tid + k * 131072;
        int row = idx >> 5, col = (idx & 31) * 4;
        float lsum = Lbuf[row] + Lbuf[16384 + row] + Lbuf[32768 + row] + Lbuf[49152 + row];
        float inv = 1.f / lsum;
        f32x4 o = *reinterpret_cast<const f32x4*>(&outO[(size_t)row * HD + col]);
        #pragma unroll
        for (int cc = 0; cc < 3; ++cc) {
            ushort4 uu = *reinterpret_cast<const ushort4*>(
                &Obf[(size_t)cc * 2097152 + (size_t)row * HD + col]);
            union { u32 u; float f; } a, b2, c2, d2;
            a.u = (u32)uu.x << 16; b2.u = (u32)uu.y << 16;
            c2.u = (u32)uu.z << 16; d2.u = (u32)uu.w << 16;
            o[0] += a.f; o[1] += b2.f; o[2] += c2.f; o[3] += d2.f;
        }
        #pragma unroll
        for (int j = 0; j < 4; ++j) o[j] *= inv;
        *reinterpret_cast<f32x4*>(&outO[(size_t)row * HD + col]) = o;
    }
}

// ---------------------------------------------------------------------------
extern "C" void kernel_launch(void* const* d_in, const int* in_sizes, int n_in,
                              void* d_out, int out_size, void* d_ws, size_t ws_size,
                              hipStream_t stream) {
    const float* x  = (const float*)d_in[0];
    const float* Wq = (const float*)d_in[1];
    const float* Wk = (const float*)d_in[2];
    const float* Wv = (const float*)d_in[3];
    float* out = (float*)d_out;

    char* ws = (char*)d_ws;
    unsigned short* Qb  = (unsigned short*)(ws);                        // 4 MB
    unsigned short* Kb  = (unsigned short*)(ws + ((size_t)4  << 20));   // 4 MB
    unsigned short* Vt  = (unsigned short*)(ws + ((size_t)8  << 20));   // 4 MB
    unsigned short* Wt  = (unsigned short*)(ws + ((size_t)12 << 20));   // 768 KB
    unsigned short* Obf = (unsigned short*)(ws + ((size_t)13 << 20));   // 3 x 4 MB
    float*          Lb  = (float*)(ws + ((size_t)25 << 20));            // 4 x 64 KB

    wt_kernel   <<<dim3(16, 3), dim3(256), 0, stream>>>(Wq, Wk, Wv, Wt);
    proj_kernel <<<dim3(768),   dim3(256), 0, stream>>>(x, Wt, Qb, Kb, Vt);
    attn_kernel <<<dim3(1024),  dim3(256), 0, stream>>>(Qb, Kb, Vt, out, Obf, Lb);
    merge_kernel<<<dim3(512),   dim3(256), 0, stream>>>(out, Obf, Lb);
}

// Round 2
// 168.113 us; speedup vs baseline: 1.4028x; 1.4028x over previous
//
#include <hip/hip_runtime.h>
#include <hip/hip_bf16.h>
#include <math.h>

#define D_MODEL 1024
#define HD 128
#define SEQ 4096

typedef __bf16 bf16x8 __attribute__((ext_vector_type(8)));
typedef float f32x4 __attribute__((ext_vector_type(4)));
typedef unsigned int u32;
typedef u32 u32x4 __attribute__((ext_vector_type(4)));

__device__ __forceinline__ unsigned short f2bf(float f) {
    union { float f; u32 u; } c; c.f = f;
    u32 u = c.u;
    u = (u + 0x7fffu + ((u >> 16) & 1u)) >> 16;
    return (unsigned short)u;
}
__device__ __forceinline__ u32 pk2(float a, float b) {
    __hip_bfloat162 h = __float22bfloat162_rn(make_float2(a, b));
    union { __hip_bfloat162 h; u32 u; } c; c.h = h; return c.u;
}
// async global->LDS, 16B/lane; dest = wave-uniform base + lane*16
__device__ __forceinline__ void dma16(void* lds, const void* g) {
    __builtin_amdgcn_global_load_lds(
        (const __attribute__((address_space(1))) u32*)g,
        (__attribute__((address_space(3))) u32*)lds, 16, 0, 0);
}
// DMA completion is tracked only in the ISSUING wave's vmcnt (R7 race).
__device__ __forceinline__ void drain_dma()  { __builtin_amdgcn_s_waitcnt(0x0F70); } // vmcnt(0)

// ---------------------------------------------------------------------------
// LDS-transposed W -> Wt[n][k] bf16, n in [0,384). Q slice pre-scaled by
// 1/sqrt(128)*log2(e): scores exit QK^T MFMA in the log2 domain.
__global__ __launch_bounds__(256)
void wt_kernel(const float* __restrict__ Wq, const float* __restrict__ Wk,
               const float* __restrict__ Wv, unsigned short* __restrict__ Wt) {
    __shared__ float wsf[64][129];
    const int t = threadIdx.x;
    const int k0 = blockIdx.x * 64;
    const int mat = blockIdx.y;
    const float* W = (mat == 0) ? Wq : (mat == 1) ? Wk : Wv;
    const float sc = (mat == 0) ? (0.08838834764831845f * 1.4426950408889634f) : 1.0f;
    {
        const int r = t >> 2, c = (t & 3) * 32;
        const float* src = W + (size_t)(k0 + r) * HD + c;
        #pragma unroll
        for (int j = 0; j < 32; j += 4)
            *reinterpret_cast<f32x4*>(&wsf[r][c + j]) = *reinterpret_cast<const f32x4*>(src + j);
    }
    __syncthreads();
    const int n = t >> 1, ks = (t & 1) * 32;
    u32 ow[16];
    #pragma unroll
    for (int j = 0; j < 16; ++j)
        ow[j] = pk2(wsf[ks + 2 * j][n] * sc, wsf[ks + 2 * j + 1][n] * sc);
    unsigned short* dst = Wt + (size_t)(mat * HD + n) * D_MODEL + k0 + ks;
    #pragma unroll
    for (int j = 0; j < 4; ++j)
        *reinterpret_cast<u32x4*>(dst + j * 8) = (u32x4){ow[4*j], ow[4*j+1], ow[4*j+2], ow[4*j+3]};
}

// ---------------------------------------------------------------------------
// QKV projection v3 (R11): FUSED Q|K|V per block, wave-owns-n, quad-buffered.
// R10 lesson: direct per-lane loads (2KB stride) splinter into 16 cacheline
// transactions each and re-read Wt 4x through the ~64B/cy L1 -> 2.5x SLOWER.
// DMA->LDS staging is the right transport; v1's real limits were (a) x fetched
// 3x from LLC (Q/K/V in separate blocks) and (b) 4x Wt LDS re-read per block.
// v3: grid 256 (1 block/CU), 512 thr; block = 64 rows x 384 cols. x staged
// once (64MB LLC total), each wave reads only its 96-col Wt slice -> chip LDS
// reads 983->459MB. Quad-buffer (128KB LDS) gives prefetch distance 3 with
// ONE barrier/iter: stage(it+3) issued right after the barrier targets the
// buffer last read at it-1 (all waves provably past it). vmcnt(8) retires
// exactly stage(it); never drains to 0 in-loop.
// LDS layout: x [4 bufs][64 rows][128B], Wt [4 bufs][192 rows][128B] where
// LDS row r packs Wt rows r and r+192 (2 halves x 4 k-granules); all granules
// XOR-swizzled by (row&7) -> 2-way max bank aliasing on ds_read_b128 (free).
__global__ __launch_bounds__(512, 2)
void proj_kernel(const float* __restrict__ x, const unsigned short* __restrict__ Wt,
                 unsigned short* __restrict__ Qb, unsigned short* __restrict__ Kb,
                 unsigned short* __restrict__ Vt) {
    __shared__ __align__(1024) char ps[131072];  // x: [0,32K) 4x8KB; Wt: [32K,128K) 4x24KB
    const int t = threadIdx.x;
    const int w = t >> 6, l = t & 63, li = l & 15, g2 = l >> 4;
    const int mh = w >> 2, nq = w & 3;           // wave owns rows mh*32..+32, cols nq*96..+96
    const int rowbase = blockIdx.x * 64;

    const int lr = l >> 3, lg = l & 7;           // dma: row-within-8, phys granule
    const int cg = lg ^ lr;                      // content code (= phys ^ (row&7))
    const int wn_add = (cg >> 2) * 192;          // Wt n-half packed in bit2
    const int wkq = (cg & 3) * 8;                // Wt k-granule (8 bf16 = 16B)

    auto stage = [&](int it) {
        const int k0 = it * 32;
        const int buf = it & 3;
        // x: wave w stages rows w*8..+8 (1 dma): LDS[r][g] = x[r][kgran g^(r&7)]
        dma16(ps + buf * 8192 + w * 1024,
              x + (size_t)(rowbase + w * 8 + lr) * D_MODEL + k0 + cg * 4);
        // Wt: wave w stages LDS rows w*24..+24 (3 dma)
        #pragma unroll
        for (int j = 0; j < 3; ++j) {
            int r0 = w * 24 + j * 8;
            dma16(ps + 32768 + buf * 24576 + r0 * 128,
                  Wt + (size_t)(r0 + lr + wn_add) * D_MODEL + k0 + wkq);
        }
    };

    f32x4 acc[2][6];
    #pragma unroll
    for (int mt = 0; mt < 2; ++mt)
        #pragma unroll
        for (int nt = 0; nt < 6; ++nt) acc[mt][nt] = (f32x4){0.f, 0.f, 0.f, 0.f};

    stage(0); stage(1); stage(2);
    for (int it = 0; it < 32; ++it) {
        if (it < 30)       __builtin_amdgcn_s_waitcnt(0x0F78);  // vmcnt(8): stage(it) landed
        else if (it == 30) __builtin_amdgcn_s_waitcnt(0x0F74);  // vmcnt(4)
        else               drain_dma();                          // vmcnt(0)
        __syncthreads();
        if (it + 3 < 32) stage(it + 3);

        const char* xb = ps + (it & 3) * 8192;
        const char* wb = ps + 32768 + (it & 3) * 24576;

        // B-frags: n = nq*96 + nt*16 + li, k = g2*8..+8; read once, reuse 2 mt
        bf16x8 bf[6];
        #pragma unroll
        for (int nt = 0; nt < 6; ++nt) {
            int r = (nq & 1) * 96 + nt * 16 + li;
            bf[nt] = *reinterpret_cast<const bf16x8*>(
                wb + r * 128 + ((((nq >> 1) * 4 + g2) ^ (li & 7)) * 16));
        }
        #pragma unroll
        for (int mt = 0; mt < 2; ++mt) {
            int row = mh * 32 + mt * 16 + li;
            int p0 = ((2 * g2) ^ (li & 7)) * 16;
            f32x4 x0 = *reinterpret_cast<const f32x4*>(xb + row * 128 + p0);
            f32x4 x1 = *reinterpret_cast<const f32x4*>(xb + row * 128 + (p0 ^ 16));
            union { u32 d[4]; bf16x8 v; } cva;
            cva.d[0] = pk2(x0[0], x0[1]); cva.d[1] = pk2(x0[2], x0[3]);
            cva.d[2] = pk2(x1[0], x1[1]); cva.d[3] = pk2(x1[2], x1[3]);
            bf16x8 af = cva.v;
            #pragma unroll
            for (int nt = 0; nt < 6; ++nt)
                acc[mt][nt] = __builtin_amdgcn_mfma_f32_16x16x32_bf16(af, bf[nt], acc[mt][nt], 0, 0, 0);
        }
    }

    // Epilogue: C row = mh*32+mt*16+g2*4+r, col = nq*96+nt*16+li
    #pragma unroll
    for (int nt = 0; nt < 6; ++nt) {
        const int c0 = nq * 96 + nt * 16;
        #pragma unroll
        for (int mt = 0; mt < 2; ++mt) {
            const int m0 = mh * 32 + mt * 16 + g2 * 4;
            if (c0 < 256) {
                unsigned short* P = (c0 < 128) ? Qb : Kb;
                const int col = (c0 < 128 ? c0 : c0 - 128) + li;
                #pragma unroll
                for (int r = 0; r < 4; ++r)
                    P[(size_t)(rowbase + m0 + r) * HD + col] = f2bf(acc[mt][nt][r]);
            } else {
                const int d = c0 - 256 + li;
                const int b_ = rowbase >> 12, s_ = (rowbase + m0) & 4095;
                ushort4 s4;
                s4.x = f2bf(acc[mt][nt][0]); s4.y = f2bf(acc[mt][nt][1]);
                s4.z = f2bf(acc[mt][nt][2]); s4.w = f2bf(acc[mt][nt][3]);
                *reinterpret_cast<ushort4*>(&Vt[((size_t)b_ * HD + d) * SEQ + s_]) = s4;
            }
        }
    }
}

// ---------------------------------------------------------------------------
// Flash causal attention, OPERAND-SWAPPED: scores computed as K.Q^T so the
// C-layout gives each lane 4 CONTIGUOUS keys for one query column. Softmax
// row-sum becomes a per-lane scalar; P^T packs to one b64 LDS write per frag;
// PV runs as A=V(d,k), B=P^T(k,q); O exits q=lane/d-contiguous -> f32x4 stores.
// Double-buffered K/V DMA staging (one barrier/iter), fixed-shift softmax.
// LDS 72 KB: K/V buf0 [0,32K), buf1 [32K,64K), P^T [64K,72K).
__global__ __launch_bounds__(256, 2)
void attn_kernel(const unsigned short* __restrict__ Qb, const unsigned short* __restrict__ Kb,
                 const unsigned short* __restrict__ Vt, float* __restrict__ outO,
                 unsigned short* __restrict__ Obf, float* __restrict__ Lbuf) {
    __shared__ __align__(1024) char smem[73728];
    const int t = threadIdx.x;
    const int w = t >> 6, l = t & 63, li = l & 15, g2 = l >> 4;
    const int qh = w >> 1, kh = w & 1;
    const int b = blockIdx.x & 3;
    const int u = blockIdx.x >> 2;
    const int g = 63 - (u >> 2);               // q-group, heavy first (LPT)
    const int c = u & 3;                       // key-range chunk
    const int R = g + 1;
    const int ts = (c * R) >> 2, te = ((c + 1) * R) >> 2;
    const int q0 = g * 64;
    const size_t rowb = (size_t)b * SEQ;
    const int koff = kh * 32;

    const unsigned short* KbB = Kb + rowb * HD;
    const unsigned short* VtB = Vt + (size_t)b * HD * SEQ;
    const int vgran = ((l & 7) ^ (l >> 3)) * 8;

    auto stage = [&](int it, char* base) {
        const int j0 = it * 64;
        #pragma unroll
        for (int j = 0; j < 4; ++j) {
            int rK = w * 16 + 4 * j + (l >> 4);
            dma16(base + (w * 16 + 4 * j) * 256,
                  KbB + (size_t)(j0 + rK) * 128 + (((l & 15) ^ (rK & 7)) * 8));
            int rV = w * 32 + 8 * j + (l >> 3);
            dma16(base + 16384 + (w * 32 + 8 * j) * 128,
                  VtB + (size_t)rV * SEQ + j0 + vgran);
        }
    };

    // Q as B-operand: B[k=d][n=q], lane n=li -> q, 8 contiguous d (= row-major load)
    bf16x8 qf[2][4];
    #pragma unroll
    for (int qt = 0; qt < 2; ++qt)
        #pragma unroll
        for (int ks = 0; ks < 4; ++ks)
            qf[qt][ks] = *reinterpret_cast<const bf16x8*>(
                Qb + (rowb + q0 + qh * 32 + qt * 16 + li) * HD + ks * 32 + g2 * 8);

    f32x4 acco[2][8];        // [qt][dt]: q=li, d=dt*16+g2*4+r
    #pragma unroll
    for (int qt = 0; qt < 2; ++qt)
        #pragma unroll
        for (int dt = 0; dt < 8; ++dt) acco[qt][dt] = (f32x4){0.f, 0.f, 0.f, 0.f};
    float ls[2] = {0.f, 0.f};   // per-lane: column q=li (per qt tile)

    const int gV = ((4 * kh + g2) ^ (li & 7)) * 16;   // V read granule offset

    if (ts < te) stage(ts, smem);
    for (int it = ts; it < te; ++it) {
        char* cbuf = smem + ((it - ts) & 1) * 32768;
        char* nbuf = smem + (((it - ts) & 1) ^ 1) * 32768;
        drain_dma();
        __syncthreads();
        if (it + 1 < te) stage(it + 1, nbuf);   // overlaps compute below

        // S^T = K.Q^T : rows=key (koff+kt*16+g2*4+r), cols=q (li)
        f32x4 accs[2][2];
        #pragma unroll
        for (int qt = 0; qt < 2; ++qt)
            #pragma unroll
            for (int kt = 0; kt < 2; ++kt) accs[qt][kt] = (f32x4){0.f, 0.f, 0.f, 0.f};
        #pragma unroll
        for (int kt = 0; kt < 2; ++kt) {
            const char* kb = cbuf + (koff + kt * 16 + li) * 256;
            #pragma unroll
            for (int ks = 0; ks < 4; ++ks) {
                bf16x8 kf = *reinterpret_cast<const bf16x8*>(kb + (((4 * ks + g2) ^ (li & 7)) * 16));
                accs[0][kt] = __builtin_amdgcn_mfma_f32_16x16x32_bf16(kf, qf[0][ks], accs[0][kt], 0, 0, 0);
                accs[1][kt] = __builtin_amdgcn_mfma_f32_16x16x32_bf16(kf, qf[1][ks], accs[1][kt], 0, 0, 0);
            }
        }

        const bool masked = (it == g);
        #pragma unroll
        for (int qt = 0; qt < 2; ++qt) {
            const int prow = qh * 32 + qt * 16 + li;       // block-local q
            #pragma unroll
            for (int kt = 0; kt < 2; ++kt) {
                float p[4];
                #pragma unroll
                for (int r = 0; r < 4; ++r) {
                    float s = accs[qt][kt][r];
                    if (masked && (koff + kt * 16 + g2 * 4 + r > prow)) s = -INFINITY;
                    p[r] = __builtin_amdgcn_exp2f(s - 16.0f);
                    ls[qt] += p[r];
                }
                // P^T[q][key] : lane writes 4 contiguous keys = one b64 store
                union { u32 d[2]; uint2 v; } pw;
                pw.d[0] = pk2(p[0], p[1]); pw.d[1] = pk2(p[2], p[3]);
                int gr = (kh * 4 + kt * 2 + (g2 >> 1)) ^ (prow & 7);
                *reinterpret_cast<uint2*>(
                    smem + 65536 + prow * 128 + gr * 16 + (g2 & 1) * 8) = pw.v;
            }
        }

        // In-wave P^T write->read only (same rows/granules); lgkmcnt orders.
        bf16x8 pb[2];
        #pragma unroll
        for (int qt = 0; qt < 2; ++qt) {
            const int prow = qh * 32 + qt * 16 + li;
            pb[qt] = *reinterpret_cast<const bf16x8*>(
                smem + 65536 + prow * 128 + (((kh * 4 + g2) ^ (prow & 7)) * 16));
        }
        #pragma unroll
        for (int dt = 0; dt < 8; ++dt) {
            bf16x8 va = *reinterpret_cast<const bf16x8*>(cbuf + 16384 + (dt * 16 + li) * 128 + gV);
            acco[0][dt] = __builtin_amdgcn_mfma_f32_16x16x32_bf16(va, pb[0], acco[0][dt], 0, 0, 0);
            acco[1][dt] = __builtin_amdgcn_mfma_f32_16x16x32_bf16(va, pb[1], acco[1][dt], 0, 0, 0);
        }
    }

    // per-lane l: combine the 4 key-quads (lanes 16 apart hold same q)
    #pragma unroll
    for (int qt = 0; qt < 2; ++qt) {
        ls[qt] += __shfl_xor(ls[qt], 16);
        ls[qt] += __shfl_xor(ls[qt], 32);
    }

    // combine kh halves via LDS overlay (stage buffers dead now)
    float (*Osum)[132] = (float(*)[132])smem;        // 64 x 128 (+4 pad) f32 = [0,33792)
    float* Lsh = (float*)(smem + 33792);             // [2][64]
    __syncthreads();
    if (l < 16) {
        Lsh[kh * 64 + qh * 32 + l]      = ls[0];
        Lsh[kh * 64 + qh * 32 + 16 + l] = ls[1];
    }
    if (kh == 0) {
        #pragma unroll
        for (int qt = 0; qt < 2; ++qt)
            #pragma unroll
            for (int dt = 0; dt < 8; ++dt)
                *reinterpret_cast<f32x4*>(
                    &Osum[qh * 32 + qt * 16 + li][dt * 16 + g2 * 4]) = acco[qt][dt];
    }
    __syncthreads();
    if (kh == 1) {
        #pragma unroll
        for (int qt = 0; qt < 2; ++qt)
            #pragma unroll
            for (int dt = 0; dt < 8; ++dt) {
                f32x4* p = reinterpret_cast<f32x4*>(
                    &Osum[qh * 32 + qt * 16 + li][dt * 16 + g2 * 4]);
                f32x4 v = *p;
                #pragma unroll
                for (int j = 0; j < 4; ++j) v[j] += acco[qt][dt][j];
                *p = v;
            }
    }
    __syncthreads();

    if (t < 64)
        Lbuf[(size_t)c * 16384 + rowb + q0 + t] = Lsh[t] + Lsh[64 + t];
    #pragma unroll
    for (int k = 0; k < 8; ++k) {
        int idx = t + k * 256;
        int row = idx >> 5, col = (idx & 31) * 4;
        f32x4 o = *reinterpret_cast<const f32x4*>(&Osum[row][col]);
        size_t grow = rowb + q0 + row;
        if (c == 3) {
            *reinterpret_cast<f32x4*>(&outO[grow * HD + col]) = o;
        } else {
            union { u32 d[2]; uint2 v; } pkd;
            pkd.d[0] = pk2(o[0], o[1]); pkd.d[1] = pk2(o[2], o[3]);
            *reinterpret_cast<uint2*>(&Obf[(size_t)c * 2097152 + grow * HD + col]) = pkd.v;
        }
    }
}

// ---------------------------------------------------------------------------
// Merge: out = (Obf[0]+Obf[1]+Obf[2]+out) / (l0+l1+l2+l3)
__global__ __launch_bounds__(256)
void merge_kernel(float* __restrict__ outO, const unsigned short* __restrict__ Obf,
                  const float* __restrict__ Lbuf) {
    int tid = blockIdx.x * 256 + threadIdx.x;
    #pragma unroll
    for (int k = 0; k < 4; ++k) {
        int idx = tid + k * 131072;
        int row = idx >> 5, col = (idx & 31) * 4;
        float lsum = Lbuf[row] + Lbuf[16384 + row] + Lbuf[32768 + row] + Lbuf[49152 + row];
        float inv = 1.f / lsum;
        f32x4 o = *reinterpret_cast<const f32x4*>(&outO[(size_t)row * HD + col]);
        #pragma unroll
        for (int cc = 0; cc < 3; ++cc) {
            ushort4 uu = *reinterpret_cast<const ushort4*>(
                &Obf[(size_t)cc * 2097152 + (size_t)row * HD + col]);
            union { u32 u; float f; } a, b2, c2, d2;
            a.u = (u32)uu.x << 16; b2.u = (u32)uu.y << 16;
            c2.u = (u32)uu.z << 16; d2.u = (u32)uu.w << 16;
            o[0] += a.f; o[1] += b2.f; o[2] += c2.f; o[3] += d2.f;
        }
        #pragma unroll
        for (int j = 0; j < 4; ++j) o[j] *= inv;
        *reinterpret_cast<f32x4*>(&outO[(size_t)row * HD + col]) = o;
    }
}

// ---------------------------------------------------------------------------
extern "C" void kernel_launch(void* const* d_in, const int* in_sizes, int n_in,
                              void* d_out, int out_size, void* d_ws, size_t ws_size,
                              hipStream_t stream) {
    const float* x  = (const float*)d_in[0];
    const float* Wq = (const float*)d_in[1];
    const float* Wk = (const float*)d_in[2];
    const float* Wv = (const float*)d_in[3];
    float* out = (float*)d_out;

    char* ws = (char*)d_ws;
    unsigned short* Qb  = (unsigned short*)(ws);                        // 4 MB
    unsigned short* Kb  = (unsigned short*)(ws + ((size_t)4  << 20));   // 4 MB
    unsigned short* Vt  = (unsigned short*)(ws + ((size_t)8  << 20));   // 4 MB
    unsigned short* Wt  = (unsigned short*)(ws + ((size_t)12 << 20));   // 768 KB
    unsigned short* Obf = (unsigned short*)(ws + ((size_t)13 << 20));   // 3 x 4 MB
    float*          Lb  = (float*)(ws + ((size_t)25 << 20));            // 4 x 64 KB

    wt_kernel   <<<dim3(16, 3), dim3(256), 0, stream>>>(Wq, Wk, Wv, Wt);
    proj_kernel <<<dim3(256),   dim3(512), 0, stream>>>(x, Wt, Qb, Kb, Vt);
    attn_kernel <<<dim3(1024),  dim3(256), 0, stream>>>(Qb, Kb, Vt, out, Obf, Lb);
    merge_kernel<<<dim3(512),   dim3(256), 0, stream>>>(out, Obf, Lb);
}